// Round 11
// baseline (252.479 us; speedup 1.0000x reference)
//
#include <hip/hip_runtime.h>

#define Bn 8
#define Tn 1024
#define Fn 512
#define Hn 8
#define DKn 64
#define Pn 2047

namespace {

typedef _Float16 h8 __attribute__((ext_vector_type(8)));
typedef float f4 __attribute__((ext_vector_type(4)));

__device__ __forceinline__ unsigned short f2h(float f) {
  _Float16 h = (_Float16)f;
  return __builtin_bit_cast(unsigned short, h);
}
__device__ __forceinline__ float h2f(unsigned short u) {
  return (float)__builtin_bit_cast(_Float16, u);
}

__device__ __forceinline__ f4 mfma16(h8 a, h8 b, f4 c) {
  return __builtin_amdgcn_mfma_f32_16x16x32_f16(a, b, c, 0, 0, 0);
}

// Read a 16B MFMA fragment from a swizzled LDS tile with 128B rows.
__device__ __forceinline__ h8 frag_ld(const unsigned char* p, int row, int kk, int grp) {
  int off = row * 128 + kk * 64 + grp * 16;
  off ^= (row & 7) << 4;
  return *(const h8*)(p + off);
}

// swizzled byte offset of element (row, d) inside a tile image with 128B rows
__device__ __forceinline__ int tile_off(int row, int d) {
  return row * 128 + (((d >> 3) << 4) ^ ((row & 7) << 4)) + (d & 7) * 2;
}

// per-thread tile copy helpers: one 8192B tile image <-> 2 uint4 per thread
__device__ __forceinline__ void tload(const unsigned char* img, int t, uint4& a, uint4& b) {
  a = *(const uint4*)(img + t * 16);
  b = *(const uint4*)(img + 4096 + t * 16);
}
__device__ __forceinline__ void tstore(unsigned char* s, int t, const uint4& a, const uint4& b) {
  *(uint4*)(s + t * 16) = a;
  *(uint4*)(s + 4096 + t * 16) = b;
}

// ---------------- mask dtype detection (bool bytes vs int32) ----------------
__global__ void detect_kernel(const unsigned int* m, int* flag) {
  if (threadIdx.x == 0) {
    int bm = 0;
    for (int i = 0; i < 256; ++i)
      if (m[i] > 1u) bm = 1;
    *flag = bm;  // 1 => byte mask, 0 => int32 mask
  }
}

// ---------------- mask -> 64-bit words: Mb[(b*T+q)*16 + kt] ----------------
__global__ __launch_bounds__(256) void maskbits_kernel(
    const void* __restrict__ maskp, const int* __restrict__ flagp,
    unsigned long long* __restrict__ Mb) {
  const int wid = (blockIdx.x * 256 + threadIdx.x) >> 6;  // row = b*1024+q
  const int l = threadIdx.x & 63;
  const int byte_mode = *flagp;
  const size_t base = (size_t)wid * Tn;
  for (int kt = 0; kt < 16; ++kt) {
    bool mv;
    if (byte_mode)
      mv = ((const unsigned char*)maskp)[base + kt * 64 + l] != 0;
    else
      mv = ((const int*)maskp)[base + kt * 64 + l] != 0;
    unsigned long long bits = __ballot(mv);
    if (l == 0) Mb[(size_t)wid * 16 + kt] = bits;
  }
}

// ---------------- weights -> fp16 prepass (each W converted ONCE) -----------
__global__ __launch_bounds__(256) void wcvt_kernel(
    const float* __restrict__ W0, const float* __restrict__ W1,
    const float* __restrict__ W2, const float* __restrict__ W3,
    const float* __restrict__ W4, unsigned short* __restrict__ Whs) {
  const float* src = blockIdx.y == 0 ? W0 : blockIdx.y == 1 ? W1
                    : blockIdx.y == 2 ? W2 : blockIdx.y == 3 ? W3 : W4;
  unsigned short* dst = Whs + (size_t)blockIdx.y * 262144;
  int i = (blockIdx.x * 256 + threadIdx.x) * 8;
  float4 a = *(const float4*)(src + i);
  float4 b = *(const float4*)(src + i + 4);
  uint4 o;
  o.x = (unsigned)f2h(a.x) | ((unsigned)f2h(a.y) << 16);
  o.y = (unsigned)f2h(a.z) | ((unsigned)f2h(a.w) << 16);
  o.z = (unsigned)f2h(b.x) | ((unsigned)f2h(b.y) << 16);
  o.w = (unsigned)f2h(b.z) | ((unsigned)f2h(b.w) << 16);
  *(uint4*)(dst + i) = o;
}

// ---------------- activations -> fp16 prepass (query/key/value/pos) ---------
// blockIdx.y: 0=query 1=key 2=value (n8=524288), 3=pos (n8=131008)
__global__ __launch_bounds__(256) void acvt_kernel(
    const float* __restrict__ A0, const float* __restrict__ A1,
    const float* __restrict__ A2, const float* __restrict__ A3,
    unsigned short* __restrict__ Ah0, unsigned short* __restrict__ Ah1,
    unsigned short* __restrict__ Ah2, unsigned short* __restrict__ Ah3) {
  const int y = blockIdx.y;
  const float* src = y == 0 ? A0 : y == 1 ? A1 : y == 2 ? A2 : A3;
  unsigned short* dst = y == 0 ? Ah0 : y == 1 ? Ah1 : y == 2 ? Ah2 : Ah3;
  const int n8 = y == 3 ? 131008 : 524288;
  int i = blockIdx.x * 256 + threadIdx.x;
  if (i >= n8) return;
  float4 a = *(const float4*)(src + (size_t)i * 8);
  float4 b = *(const float4*)(src + (size_t)i * 8 + 4);
  uint4 o;
  o.x = (unsigned)f2h(a.x) | ((unsigned)f2h(a.y) << 16);
  o.y = (unsigned)f2h(a.z) | ((unsigned)f2h(a.w) << 16);
  o.z = (unsigned)f2h(b.x) | ((unsigned)f2h(b.y) << 16);
  o.w = (unsigned)f2h(b.z) | ((unsigned)f2h(b.w) << 16);
  *(uint4*)(dst + (size_t)i * 8) = o;
}

// ---------------- merged Q/K/V/pos projection: C = A @ W^T (+bias) ----------
// A and W both pre-converted fp16. blockIdx.z: 0=Q, 1=K, 2=V, 3=pos
__global__ __launch_bounds__(256) void qkvp_kernel(
    const unsigned short* __restrict__ Ahq, const unsigned short* __restrict__ Ahk,
    const unsigned short* __restrict__ Ahv, const unsigned short* __restrict__ Ahp,
    const unsigned short* __restrict__ Whs,
    const float* __restrict__ bq, const float* __restrict__ bk,
    const float* __restrict__ bv,
    const float* __restrict__ pbu, const float* __restrict__ pbv,
    unsigned short* __restrict__ Qu, unsigned short* __restrict__ Qv,
    unsigned char* __restrict__ Kws, unsigned char* __restrict__ Vws,
    unsigned char* __restrict__ Pws) {
  const int mode = blockIdx.z;
  if (mode == 3 && blockIdx.x >= 32) return;
  const unsigned short* A = mode == 0 ? Ahq : mode == 1 ? Ahk : mode == 2 ? Ahv : Ahp;
  const unsigned short* Wh = Whs + (size_t)mode * 262144;
  const float* bias = mode == 0 ? bq : mode == 1 ? bk : bv;
  const int M = mode == 3 ? Pn : Bn * Tn;

  __shared__ __align__(16) unsigned char sA[64 * 128];
  __shared__ __align__(16) unsigned char sB[64 * 128];

  const int t = threadIdx.x;
  const int w = t >> 6, l = t & 63;
  const int grp = l >> 4, lc = l & 15;
  const int m0 = blockIdx.x * 64, n0 = blockIdx.y * 64;
  const int srow = t >> 2, sseg = t & 3;

  f4 acc[4];
#pragma unroll
  for (int c = 0; c < 4; ++c) acc[c] = {0.f, 0.f, 0.f, 0.f};

  for (int kt = 0; kt < 8; ++kt) {
    {
      int gm = m0 + srow;
      int sw = (srow & 7) << 4;
      bool valid = (gm < M);
      const unsigned short* ar = A + (size_t)gm * Fn + kt * 64 + sseg * 16;
      const uint4 z4 = make_uint4(0, 0, 0, 0);
#pragma unroll
      for (int hh = 0; hh < 2; ++hh) {
        uint4 qd = valid ? *(const uint4*)(ar + hh * 8) : z4;
        int off = srow * 128 + sseg * 32 + hh * 16;
        *(uint2*)(sA + ((off) ^ sw)) = make_uint2(qd.x, qd.y);
        *(uint2*)(sA + ((off + 8) ^ sw)) = make_uint2(qd.z, qd.w);
      }
      const unsigned short* br = Wh + (size_t)(n0 + srow) * Fn + kt * 64 + sseg * 16;
#pragma unroll
      for (int hh = 0; hh < 2; ++hh) {
        uint4 qd = *(const uint4*)(br + hh * 8);
        int off = srow * 128 + sseg * 32 + hh * 16;
        *(uint2*)(sB + ((off) ^ sw)) = make_uint2(qd.x, qd.y);
        *(uint2*)(sB + ((off + 8) ^ sw)) = make_uint2(qd.z, qd.w);
      }
    }
    __syncthreads();
    const int arow = 16 * w + lc;
    h8 a0 = frag_ld(sA, arow, 0, grp);
    h8 a1 = frag_ld(sA, arow, 1, grp);
#pragma unroll
    for (int c = 0; c < 4; ++c) {
      int brow = 16 * c + lc;
      acc[c] = mfma16(a0, frag_ld(sB, brow, 0, grp), acc[c]);
      acc[c] = mfma16(a1, frag_ld(sB, brow, 1, grp), acc[c]);
    }
    __syncthreads();
  }

#pragma unroll
  for (int c = 0; c < 4; ++c) {
#pragma unroll
    for (int r = 0; r < 4; ++r) {
      int m = m0 + 16 * w + grp * 4 + r;
      int n = n0 + 16 * c + lc;
      float vv = acc[c][r];
      if (mode == 0) {
        vv += bias[n];
        int b = m >> 10, tt = m & 1023, h = n >> 6, d = n & 63;
        size_t qi = ((size_t)(b * Hn + h) * Tn + tt) * DKn + d;
        Qu[qi] = f2h(vv + pbu[n]);
        Qv[qi] = f2h(vv + pbv[n]);
      } else if (mode == 1) {
        vv += bias[n];
        int b = m >> 10, tt = m & 1023, h = n >> 6, d = n & 63;
        size_t off = (((size_t)(b * Hn + h) * 16 + (tt >> 6)) << 13) + tile_off(tt & 63, d);
        *(unsigned short*)(Kws + off) = f2h(vv);
      } else if (mode == 2) {
        vv += bias[n];
        int b = m >> 10, tt = m & 1023, h = n >> 6, d = n & 63;
        size_t off = (((size_t)(b * Hn + h) * 16 + (tt >> 6)) << 13) + tile_off(d, tt & 63);
        *(unsigned short*)(Vws + off) = f2h(vv);
      } else {
        int h = n >> 6, d = n & 63;
        size_t off = (((size_t)h * 32 + (m >> 6)) << 13) + tile_off(m & 63, d);
        // m == Pn (row 2047) is never consumed as a score; write 0 (no poison)
        *(unsigned short*)(Pws + off) = f2h(m < M ? vv : 0.f);
      }
    }
  }
}

// ---------------- output projection: out = x @ Wo^T + bo (x, Wo fp16) -------
__global__ __launch_bounds__(256) void oproj_kernel(
    const unsigned short* __restrict__ Ah, const unsigned short* __restrict__ Wh,
    const float* __restrict__ bias, float* __restrict__ ofp) {
  __shared__ __align__(16) unsigned char sA[64 * 128];
  __shared__ __align__(16) unsigned char sB[64 * 128];

  const int t = threadIdx.x;
  const int w = t >> 6, l = t & 63;
  const int grp = l >> 4, lc = l & 15;
  const int m0 = blockIdx.x * 64, n0 = blockIdx.y * 64;
  const int srow = t >> 2, sseg = t & 3;

  f4 acc[4];
#pragma unroll
  for (int c = 0; c < 4; ++c) acc[c] = {0.f, 0.f, 0.f, 0.f};

  for (int kt = 0; kt < 8; ++kt) {
    {
      int sw = (srow & 7) << 4;
      const unsigned short* ar = Ah + (size_t)(m0 + srow) * Fn + kt * 64 + sseg * 16;
#pragma unroll
      for (int hh = 0; hh < 2; ++hh) {
        uint4 qd = *(const uint4*)(ar + hh * 8);
        int off = srow * 128 + sseg * 32 + hh * 16;
        *(uint2*)(sA + ((off) ^ sw)) = make_uint2(qd.x, qd.y);
        *(uint2*)(sA + ((off + 8) ^ sw)) = make_uint2(qd.z, qd.w);
      }
      const unsigned short* br = Wh + (size_t)(n0 + srow) * Fn + kt * 64 + sseg * 16;
#pragma unroll
      for (int hh = 0; hh < 2; ++hh) {
        uint4 qd = *(const uint4*)(br + hh * 8);
        int off = srow * 128 + sseg * 32 + hh * 16;
        *(uint2*)(sB + ((off) ^ sw)) = make_uint2(qd.x, qd.y);
        *(uint2*)(sB + ((off + 8) ^ sw)) = make_uint2(qd.z, qd.w);
      }
    }
    __syncthreads();
    const int arow = 16 * w + lc;
    h8 a0 = frag_ld(sA, arow, 0, grp);
    h8 a1 = frag_ld(sA, arow, 1, grp);
#pragma unroll
    for (int c = 0; c < 4; ++c) {
      int brow = 16 * c + lc;
      acc[c] = mfma16(a0, frag_ld(sB, brow, 0, grp), acc[c]);
      acc[c] = mfma16(a1, frag_ld(sB, brow, 1, grp), acc[c]);
    }
    __syncthreads();
  }

#pragma unroll
  for (int c = 0; c < 4; ++c) {
#pragma unroll
    for (int r = 0; r < 4; ++r) {
      int m = m0 + 16 * w + grp * 4 + r;
      int n = 16 * c + lc + n0;
      ofp[(size_t)m * Fn + n] = acc[c][r] + bias[n];
    }
  }
}

// ---------------- fused rel-pos flash attention, reg-staged 2-barrier -------
// R4's online-max softmax (FROZEN — every restructure attempt failed on HW).
// XCD-aware swizzle; s_setprio(1) around MFMA clusters (T5, semantic-free).
__global__ __launch_bounds__(256, 3) void attn_kernel(
    const unsigned short* __restrict__ Qu, const unsigned short* __restrict__ Qv,
    const unsigned char* __restrict__ Kws, const unsigned char* __restrict__ Vws,
    const unsigned char* __restrict__ Pws, const unsigned long long* __restrict__ Mb,
    unsigned short* __restrict__ xb) {
  __shared__ __align__(16) unsigned char smem[52480];

  const int t = threadIdx.x;
  const int w = t >> 6, l = t & 63;
  const int grp = l >> 4, lc = l & 15;
  const int lin = blockIdx.x;                    // 0..1023
  const int swz = (lin & 7) * 128 + (lin >> 3);  // bijective XCD swizzle
  const int q0 = (swz & 15) * 64;
  const int bh = swz >> 4;
  const int b = bh >> 3, h = bh & 7;

  unsigned char* sK = smem;
  unsigned char* sV = smem + 8192;
  unsigned char* sP = smem + 16384;  // + (seg&1)*8192
  unsigned char* bdw = smem + 32768 + w * 2880;
  unsigned char* ppw = smem + 44288 + w * 2048;

  const unsigned char* Kg = Kws + ((size_t)bh << 17);
  const unsigned char* Vg = Vws + ((size_t)bh << 17);
  const unsigned char* Pg = Pws + ((size_t)h << 18);
  const int s0 = 15 - (q0 >> 6);

  // Q fragments for this wave's 16 q-rows
  h8 au[2], av[2];
  {
    const size_t qbase = ((size_t)bh * Tn + q0 + 16 * w + lc) * DKn;
#pragma unroll
    for (int kk = 0; kk < 2; ++kk) {
      au[kk] = *(const h8*)(Qu + qbase + kk * 32 + grp * 8);
      av[kk] = *(const h8*)(Qv + qbase + kk * 32 + grp * 8);
    }
  }

  // prologue: stage K0, V0, P segs s0 and s0+1 through registers
  {
    uint4 ka, kb, va, vb, pa, pb, pc, pd;
    tload(Kg, t, ka, kb);
    tload(Vg, t, va, vb);
    tload(Pg + ((size_t)s0 << 13), t, pa, pb);
    tload(Pg + ((size_t)(s0 + 1) << 13), t, pc, pd);
    tstore(sK, t, ka, kb);
    tstore(sV, t, va, vb);
    tstore(sP + ((s0 & 1) << 13), t, pa, pb);
    tstore(sP + (((s0 + 1) & 1) << 13), t, pc, pd);
  }
  __syncthreads();

  float m_run[4], l_run[4];
  f4 oacc[4];
#pragma unroll
  for (int r = 0; r < 4; ++r) { m_run[r] = -1e30f; l_run[r] = 0.f; }
#pragma unroll
  for (int c = 0; c < 4; ++c) oacc[c] = {0.f, 0.f, 0.f, 0.f};

  const size_t mrowbase = ((size_t)(b << 10) + q0 + 16 * w) * 16;

  for (int kt = 0; kt < 16; ++kt) {
    const int k0 = kt * 64;
    const bool more = kt < 15;

    // ---- issue next-tile loads into registers (latency hides under compute)
    uint4 ka, kb, va, vb, pa, pb;
    if (more) {
      tload(Kg + ((size_t)(kt + 1) << 13), t, ka, kb);
      tload(Vg + ((size_t)(kt + 1) << 13), t, va, vb);
      tload(Pg + ((size_t)(s0 + kt + 2) << 13), t, pa, pb);
    }

    // ---- AC: Q_u . K^T from sK ----
    __builtin_amdgcn_s_setprio(1);
    f4 ac[4];
#pragma unroll
    for (int c = 0; c < 4; ++c) {
      int brow = 16 * c + lc;
      ac[c] = {0.f, 0.f, 0.f, 0.f};
      ac[c] = mfma16(au[0], frag_ld(sK, brow, 0, grp), ac[c]);
      ac[c] = mfma16(au[1], frag_ld(sK, brow, 1, grp), ac[c]);
    }
    __builtin_amdgcn_s_setprio(0);

    // ---- BD: Q_v . P^T over wave-local 80-row window ----
    const int pbase = k0 - q0 + 960;
    const int wbase = 48 - 16 * w;
#pragma unroll
    for (int c2 = 0; c2 < 5; ++c2) {
      int prow0 = pbase + wbase + 16 * c2;
      const unsigned char* slot = sP + ((((unsigned)prow0 >> 6) & 1) << 13);
      int rloc = prow0 & 63;
      f4 z = {0.f, 0.f, 0.f, 0.f};
      z = mfma16(av[0], frag_ld(slot, rloc + lc, 0, grp), z);
      z = mfma16(av[1], frag_ld(slot, rloc + lc, 1, grp), z);
      unsigned lo = (unsigned)f2h(z[0]) | ((unsigned)f2h(z[1]) << 16);
      unsigned hi = (unsigned)f2h(z[2]) | ((unsigned)f2h(z[3]) << 16);
      unsigned char* dst = bdw + (size_t)(((16 * c2 + lc) * 18 + grp * 4) * 2);
      *(unsigned*)dst = lo;
      *(unsigned*)(dst + 4) = hi;
    }

    // ---- score + online softmax (log2 domain) ----
#pragma unroll
    for (int r = 0; r < 4; ++r) {
      const int rr = grp * 4 + r;
      const unsigned long long m64 = Mb[mrowbase + (size_t)rr * 16 + kt];
      float sc[4];
#pragma unroll
      for (int c = 0; c < 4; ++c) {
        const int col = 16 * c + lc;
        float bdf = h2f(*(const unsigned short*)(bdw + (size_t)(((col - rr + 15) * 18 + rr) * 2)));
        float vv = (ac[c][r] + bdf) * 0.18033688f;  // 0.125 * log2(e)
        sc[c] = ((m64 >> col) & 1ull) ? -14427.0f : vv;
      }
      float mx = fmaxf(fmaxf(sc[0], sc[1]), fmaxf(sc[2], sc[3]));
#pragma unroll
      for (int d2 = 1; d2 < 16; d2 <<= 1) mx = fmaxf(mx, __shfl_xor(mx, d2, 64));
      float mnew = fmaxf(m_run[r], mx);
      float scl = exp2f(m_run[r] - mnew);
      float ps = 0.f;
      unsigned short ph[4];
#pragma unroll
      for (int c = 0; c < 4; ++c) {
        float p = exp2f(sc[c] - mnew);
        ps += p;
        ph[c] = f2h(p);
      }
#pragma unroll
      for (int d2 = 1; d2 < 16; d2 <<= 1) ps += __shfl_xor(ps, d2, 64);
      l_run[r] = l_run[r] * scl + ps;
      m_run[r] = mnew;
#pragma unroll
      for (int c = 0; c < 4; ++c) oacc[c][r] *= scl;
      const int sw = (rr & 7) << 4;
#pragma unroll
      for (int c = 0; c < 4; ++c) {
        int off = (rr * 128 + (16 * c + lc) * 2) ^ sw;
        *(unsigned short*)(ppw + off) = ph[c];
      }
    }

    // ---- PV from sV (tile kt) + own ppw ----
    {
      __builtin_amdgcn_s_setprio(1);
      h8 pa0 = frag_ld(ppw, lc, 0, grp);
      h8 pa1 = frag_ld(ppw, lc, 1, grp);
#pragma unroll
      for (int c = 0; c < 4; ++c) {
        int brow = 16 * c + lc;
        oacc[c] = mfma16(pa0, frag_ld(sV, brow, 0, grp), oacc[c]);
        oacc[c] = mfma16(pa1, frag_ld(sV, brow, 1, grp), oacc[c]);
      }
      __builtin_amdgcn_s_setprio(0);
    }

    // ---- staged writes between barriers; single-buffered everywhere ----
    if (more) {
      __syncthreads();  // all waves done reading sK/sV/sP for tile kt
      tstore(sK, t, ka, kb);
      tstore(sV, t, va, vb);
      tstore(sP + (((s0 + kt) & 1) << 13), t, pa, pb);  // seg s0+kt+2 -> its parity slot
      __syncthreads();  // writes visible before next tile's reads
    }
  }

  // ---- epilogue: x[b][t][h*64+d] fp16 ----
#pragma unroll
  for (int c = 0; c < 4; ++c) {
#pragma unroll
    for (int r = 0; r < 4; ++r) {
      int rowq = 16 * w + grp * 4 + r;
      float vv = oacc[c][r] / l_run[r];
      size_t idx = ((size_t)b * Tn + q0 + rowq) * Fn + h * DKn + 16 * c + lc;
      xb[idx] = f2h(vv);
    }
  }
}

}  // namespace

extern "C" void kernel_launch(void* const* d_in, const int* in_sizes, int n_in,
                              void* d_out, int out_size, void* d_ws, size_t ws_size,
                              hipStream_t stream) {
  const float* query = (const float*)d_in[0];
  const float* key = (const float*)d_in[1];
  const float* value = (const float*)d_in[2];
  const void* maskp = d_in[3];
  const float* pos = (const float*)d_in[4];
  const float* Wq = (const float*)d_in[5];
  const float* bq = (const float*)d_in[6];
  const float* Wk = (const float*)d_in[7];
  const float* bk = (const float*)d_in[8];
  const float* Wv = (const float*)d_in[9];
  const float* bv = (const float*)d_in[10];
  const float* Wpos = (const float*)d_in[11];
  const float* Wo = (const float*)d_in[12];
  const float* bo = (const float*)d_in[13];
  const float* pu = (const float*)d_in[14];
  const float* pv = (const float*)d_in[15];
  float* out = (float*)d_out;

  unsigned char* ws = (unsigned char*)d_ws;
  int* flag = (int*)ws;
  size_t o = 256;
  unsigned short* Whs = (unsigned short*)(ws + o); o += (size_t)5 * 262144 * 2;
  unsigned long long* Mb = (unsigned long long*)(ws + o); o += (size_t)Bn * Tn * 16 * 8;
  unsigned short* Ahq = (unsigned short*)(ws + o); o += (size_t)Bn * Tn * Fn * 2;
  unsigned short* Ahk = (unsigned short*)(ws + o); o += (size_t)Bn * Tn * Fn * 2;
  unsigned short* Ahv = (unsigned short*)(ws + o); o += (size_t)Bn * Tn * Fn * 2;
  unsigned short* Ahp = (unsigned short*)(ws + o); o += (size_t)Pn * Fn * 2 + 1024;
  unsigned short* Qu = (unsigned short*)(ws + o); o += (size_t)Bn * Hn * Tn * DKn * 2;
  unsigned short* Qv = (unsigned short*)(ws + o); o += (size_t)Bn * Hn * Tn * DKn * 2;
  unsigned char* Kws = ws + o; o += (size_t)Bn * Hn * 16 * 8192;
  unsigned char* Vws = ws + o; o += (size_t)Bn * Hn * 16 * 8192;
  unsigned char* Pws = ws + o; o += (size_t)Hn * 32 * 8192;
  unsigned short* xb = (unsigned short*)(ws + o);

  detect_kernel<<<dim3(1), dim3(64), 0, stream>>>((const unsigned int*)maskp, flag);
  maskbits_kernel<<<dim3(2048), dim3(256), 0, stream>>>(maskp, flag, Mb);
  wcvt_kernel<<<dim3(128, 5), dim3(256), 0, stream>>>(Wq, Wk, Wv, Wpos, Wo, Whs);
  acvt_kernel<<<dim3(2048, 4), dim3(256), 0, stream>>>(query, key, value, pos,
                                                       Ahq, Ahk, Ahv, Ahp);
  qkvp_kernel<<<dim3(128, 8, 4), dim3(256), 0, stream>>>(
      Ahq, Ahk, Ahv, Ahp, Whs, bq, bk, bv, pu, pv,
      Qu, Qv, Kws, Vws, Pws);
  attn_kernel<<<dim3(1024), dim3(256), 0, stream>>>(Qu, Qv, Kws, Vws, Pws, Mb, xb);
  oproj_kernel<<<dim3(128, 8), dim3(256), 0, stream>>>(xb, Whs + 4 * 262144, bo, out);
}

// Round 12
// 195.249 us; speedup vs baseline: 1.2931x; 1.2931x over previous
//
#include <hip/hip_runtime.h>

#define Bn 8
#define Tn 1024
#define Fn 512
#define Hn 8
#define DKn 64
#define Pn 2047

namespace {

typedef _Float16 h8 __attribute__((ext_vector_type(8)));
typedef float f4 __attribute__((ext_vector_type(4)));

__device__ __forceinline__ unsigned short f2h(float f) {
  _Float16 h = (_Float16)f;
  return __builtin_bit_cast(unsigned short, h);
}
__device__ __forceinline__ float h2f(unsigned short u) {
  return (float)__builtin_bit_cast(_Float16, u);
}

__device__ __forceinline__ f4 mfma16(h8 a, h8 b, f4 c) {
  return __builtin_amdgcn_mfma_f32_16x16x32_f16(a, b, c, 0, 0, 0);
}

// Read a 16B MFMA fragment from a swizzled LDS tile with 128B rows.
__device__ __forceinline__ h8 frag_ld(const unsigned char* p, int row, int kk, int grp) {
  int off = row * 128 + kk * 64 + grp * 16;
  off ^= (row & 7) << 4;
  return *(const h8*)(p + off);
}

// swizzled byte offset of element (row, d) inside a tile image with 128B rows
__device__ __forceinline__ int tile_off(int row, int d) {
  return row * 128 + (((d >> 3) << 4) ^ ((row & 7) << 4)) + (d & 7) * 2;
}

// per-thread tile copy helpers: one 8192B tile image <-> 2 uint4 per thread
__device__ __forceinline__ void tload(const unsigned char* img, int t, uint4& a, uint4& b) {
  a = *(const uint4*)(img + t * 16);
  b = *(const uint4*)(img + 4096 + t * 16);
}
__device__ __forceinline__ void tstore(unsigned char* s, int t, const uint4& a, const uint4& b) {
  *(uint4*)(s + t * 16) = a;
  *(uint4*)(s + 4096 + t * 16) = b;
}

// ---------------- mask dtype detection (bool bytes vs int32) ----------------
__global__ void detect_kernel(const unsigned int* m, int* flag) {
  if (threadIdx.x == 0) {
    int bm = 0;
    for (int i = 0; i < 256; ++i)
      if (m[i] > 1u) bm = 1;
    *flag = bm;  // 1 => byte mask, 0 => int32 mask
  }
}

// ---------------- mask -> 64-bit words: Mb[(b*T+q)*16 + kt] ----------------
__global__ __launch_bounds__(256) void maskbits_kernel(
    const void* __restrict__ maskp, const int* __restrict__ flagp,
    unsigned long long* __restrict__ Mb) {
  const int wid = (blockIdx.x * 256 + threadIdx.x) >> 6;  // row = b*1024+q
  const int l = threadIdx.x & 63;
  const int byte_mode = *flagp;
  const size_t base = (size_t)wid * Tn;
  for (int kt = 0; kt < 16; ++kt) {
    bool mv;
    if (byte_mode)
      mv = ((const unsigned char*)maskp)[base + kt * 64 + l] != 0;
    else
      mv = ((const int*)maskp)[base + kt * 64 + l] != 0;
    unsigned long long bits = __ballot(mv);
    if (l == 0) Mb[(size_t)wid * 16 + kt] = bits;
  }
}

// ---------------- weights -> fp16 prepass (each W converted ONCE) -----------
__global__ __launch_bounds__(256) void wcvt_kernel(
    const float* __restrict__ W0, const float* __restrict__ W1,
    const float* __restrict__ W2, const float* __restrict__ W3,
    const float* __restrict__ W4, unsigned short* __restrict__ Whs) {
  const float* src = blockIdx.y == 0 ? W0 : blockIdx.y == 1 ? W1
                    : blockIdx.y == 2 ? W2 : blockIdx.y == 3 ? W3 : W4;
  unsigned short* dst = Whs + (size_t)blockIdx.y * 262144;
  int i = (blockIdx.x * 256 + threadIdx.x) * 8;
  float4 a = *(const float4*)(src + i);
  float4 b = *(const float4*)(src + i + 4);
  uint4 o;
  o.x = (unsigned)f2h(a.x) | ((unsigned)f2h(a.y) << 16);
  o.y = (unsigned)f2h(a.z) | ((unsigned)f2h(a.w) << 16);
  o.z = (unsigned)f2h(b.x) | ((unsigned)f2h(b.y) << 16);
  o.w = (unsigned)f2h(b.z) | ((unsigned)f2h(b.w) << 16);
  *(uint4*)(dst + i) = o;
}

// ---------------- merged Q/K/V/pos projection: C = A @ W^T (+bias) ----------
// blockIdx.z: 0=Q (Qu,Qv), 1=K, 2=V, 3=pos  (K/V/P as swizzled tile images)
__global__ __launch_bounds__(256) void qkvp_kernel(
    const float* __restrict__ Aq, const float* __restrict__ Ak,
    const float* __restrict__ Av, const float* __restrict__ Ap,
    const unsigned short* __restrict__ Whs,
    const float* __restrict__ bq, const float* __restrict__ bk,
    const float* __restrict__ bv,
    const float* __restrict__ pbu, const float* __restrict__ pbv,
    unsigned short* __restrict__ Qu, unsigned short* __restrict__ Qv,
    unsigned char* __restrict__ Kws, unsigned char* __restrict__ Vws,
    unsigned char* __restrict__ Pws) {
  const int mode = blockIdx.z;
  if (mode == 3 && blockIdx.x >= 32) return;
  const float* A = mode == 0 ? Aq : mode == 1 ? Ak : mode == 2 ? Av : Ap;
  const unsigned short* Wh = Whs + (size_t)mode * 262144;
  const float* bias = mode == 0 ? bq : mode == 1 ? bk : bv;
  const int M = mode == 3 ? Pn : Bn * Tn;

  __shared__ __align__(16) unsigned char sA[64 * 128];
  __shared__ __align__(16) unsigned char sB[64 * 128];

  const int t = threadIdx.x;
  const int w = t >> 6, l = t & 63;
  const int grp = l >> 4, lc = l & 15;
  const int m0 = blockIdx.x * 64, n0 = blockIdx.y * 64;
  const int srow = t >> 2, sseg = t & 3;

  f4 acc[4];
#pragma unroll
  for (int c = 0; c < 4; ++c) acc[c] = {0.f, 0.f, 0.f, 0.f};

  for (int kt = 0; kt < 8; ++kt) {
    {
      int gm = m0 + srow;
      int sw = (srow & 7) << 4;
      bool valid = (gm < M);
      const float* ar = A + (size_t)gm * Fn + kt * 64 + sseg * 16;
#pragma unroll
      for (int i = 0; i < 4; ++i) {
        float4 fv = valid ? *(const float4*)(ar + 4 * i) : make_float4(0.f, 0.f, 0.f, 0.f);
        uint2 pk;
        pk.x = (unsigned)f2h(fv.x) | ((unsigned)f2h(fv.y) << 16);
        pk.y = (unsigned)f2h(fv.z) | ((unsigned)f2h(fv.w) << 16);
        int off = srow * 128 + sseg * 32 + i * 8;
        *(uint2*)(sA + (off ^ sw)) = pk;
      }
      const unsigned short* br = Wh + (size_t)(n0 + srow) * Fn + kt * 64 + sseg * 16;
#pragma unroll
      for (int hh = 0; hh < 2; ++hh) {
        uint4 qd = *(const uint4*)(br + hh * 8);
        int off = srow * 128 + sseg * 32 + hh * 16;
        *(uint2*)(sB + ((off) ^ sw)) = make_uint2(qd.x, qd.y);
        *(uint2*)(sB + ((off + 8) ^ sw)) = make_uint2(qd.z, qd.w);
      }
    }
    __syncthreads();
    const int arow = 16 * w + lc;
    h8 a0 = frag_ld(sA, arow, 0, grp);
    h8 a1 = frag_ld(sA, arow, 1, grp);
#pragma unroll
    for (int c = 0; c < 4; ++c) {
      int brow = 16 * c + lc;
      acc[c] = mfma16(a0, frag_ld(sB, brow, 0, grp), acc[c]);
      acc[c] = mfma16(a1, frag_ld(sB, brow, 1, grp), acc[c]);
    }
    __syncthreads();
  }

#pragma unroll
  for (int c = 0; c < 4; ++c) {
#pragma unroll
    for (int r = 0; r < 4; ++r) {
      int m = m0 + 16 * w + grp * 4 + r;
      int n = n0 + 16 * c + lc;
      float vv = acc[c][r];
      if (mode == 0) {
        vv += bias[n];
        int b = m >> 10, tt = m & 1023, h = n >> 6, d = n & 63;
        size_t qi = ((size_t)(b * Hn + h) * Tn + tt) * DKn + d;
        Qu[qi] = f2h(vv + pbu[n]);
        Qv[qi] = f2h(vv + pbv[n]);
      } else if (mode == 1) {
        vv += bias[n];
        int b = m >> 10, tt = m & 1023, h = n >> 6, d = n & 63;
        size_t off = (((size_t)(b * Hn + h) * 16 + (tt >> 6)) << 13) + tile_off(tt & 63, d);
        *(unsigned short*)(Kws + off) = f2h(vv);
      } else if (mode == 2) {
        vv += bias[n];
        int b = m >> 10, tt = m & 1023, h = n >> 6, d = n & 63;
        size_t off = (((size_t)(b * Hn + h) * 16 + (tt >> 6)) << 13) + tile_off(d, tt & 63);
        *(unsigned short*)(Vws + off) = f2h(vv);
      } else {
        int h = n >> 6, d = n & 63;
        size_t off = (((size_t)h * 32 + (m >> 6)) << 13) + tile_off(m & 63, d);
        // m == Pn (row 2047) is never consumed as a score; write 0 (no poison)
        *(unsigned short*)(Pws + off) = f2h(m < M ? vv : 0.f);
      }
    }
  }
}

// ---------------- output projection: out = x @ Wo^T + bo (x, Wo fp16) -------
__global__ __launch_bounds__(256) void oproj_kernel(
    const unsigned short* __restrict__ Ah, const unsigned short* __restrict__ Wh,
    const float* __restrict__ bias, float* __restrict__ ofp) {
  __shared__ __align__(16) unsigned char sA[64 * 128];
  __shared__ __align__(16) unsigned char sB[64 * 128];

  const int t = threadIdx.x;
  const int w = t >> 6, l = t & 63;
  const int grp = l >> 4, lc = l & 15;
  const int m0 = blockIdx.x * 64, n0 = blockIdx.y * 64;
  const int srow = t >> 2, sseg = t & 3;

  f4 acc[4];
#pragma unroll
  for (int c = 0; c < 4; ++c) acc[c] = {0.f, 0.f, 0.f, 0.f};

  for (int kt = 0; kt < 8; ++kt) {
    {
      int sw = (srow & 7) << 4;
      const unsigned short* ar = Ah + (size_t)(m0 + srow) * Fn + kt * 64 + sseg * 16;
#pragma unroll
      for (int hh = 0; hh < 2; ++hh) {
        uint4 qd = *(const uint4*)(ar + hh * 8);
        int off = srow * 128 + sseg * 32 + hh * 16;
        *(uint2*)(sA + ((off) ^ sw)) = make_uint2(qd.x, qd.y);
        *(uint2*)(sA + ((off + 8) ^ sw)) = make_uint2(qd.z, qd.w);
      }
      const unsigned short* br = Wh + (size_t)(n0 + srow) * Fn + kt * 64 + sseg * 16;
#pragma unroll
      for (int hh = 0; hh < 2; ++hh) {
        uint4 qd = *(const uint4*)(br + hh * 8);
        int off = srow * 128 + sseg * 32 + hh * 16;
        *(uint2*)(sB + ((off) ^ sw)) = make_uint2(qd.x, qd.y);
        *(uint2*)(sB + ((off + 8) ^ sw)) = make_uint2(qd.z, qd.w);
      }
    }
    __syncthreads();
    const int arow = 16 * w + lc;
    h8 a0 = frag_ld(sA, arow, 0, grp);
    h8 a1 = frag_ld(sA, arow, 1, grp);
#pragma unroll
    for (int c = 0; c < 4; ++c) {
      int brow = 16 * c + lc;
      acc[c] = mfma16(a0, frag_ld(sB, brow, 0, grp), acc[c]);
      acc[c] = mfma16(a1, frag_ld(sB, brow, 1, grp), acc[c]);
    }
    __syncthreads();
  }

#pragma unroll
  for (int c = 0; c < 4; ++c) {
#pragma unroll
    for (int r = 0; r < 4; ++r) {
      int m = m0 + 16 * w + grp * 4 + r;
      int n = 16 * c + lc + n0;
      ofp[(size_t)m * Fn + n] = acc[c][r] + bias[n];
    }
  }
}

// ---------------- fused rel-pos flash attention, reg-staged 2-barrier -------
// R4's online-max softmax (FROZEN). XCD-aware block swizzle. No setprio.
__global__ __launch_bounds__(256, 3) void attn_kernel(
    const unsigned short* __restrict__ Qu, const unsigned short* __restrict__ Qv,
    const unsigned char* __restrict__ Kws, const unsigned char* __restrict__ Vws,
    const unsigned char* __restrict__ Pws, const unsigned long long* __restrict__ Mb,
    unsigned short* __restrict__ xb) {
  __shared__ __align__(16) unsigned char smem[52480];

  const int t = threadIdx.x;
  const int w = t >> 6, l = t & 63;
  const int grp = l >> 4, lc = l & 15;
  const int lin = blockIdx.x;                    // 0..1023
  const int swz = (lin & 7) * 128 + (lin >> 3);  // bijective XCD swizzle
  const int q0 = (swz & 15) * 64;
  const int bh = swz >> 4;
  const int b = bh >> 3, h = bh & 7;

  unsigned char* sK = smem;
  unsigned char* sV = smem + 8192;
  unsigned char* sP = smem + 16384;  // + (seg&1)*8192
  unsigned char* bdw = smem + 32768 + w * 2880;
  unsigned char* ppw = smem + 44288 + w * 2048;

  const unsigned char* Kg = Kws + ((size_t)bh << 17);
  const unsigned char* Vg = Vws + ((size_t)bh << 17);
  const unsigned char* Pg = Pws + ((size_t)h << 18);
  const int s0 = 15 - (q0 >> 6);

  // Q fragments for this wave's 16 q-rows
  h8 au[2], av[2];
  {
    const size_t qbase = ((size_t)bh * Tn + q0 + 16 * w + lc) * DKn;
#pragma unroll
    for (int kk = 0; kk < 2; ++kk) {
      au[kk] = *(const h8*)(Qu + qbase + kk * 32 + grp * 8);
      av[kk] = *(const h8*)(Qv + qbase + kk * 32 + grp * 8);
    }
  }

  // prologue: stage K0, V0, P segs s0 and s0+1 through registers
  {
    uint4 ka, kb, va, vb, pa, pb, pc, pd;
    tload(Kg, t, ka, kb);
    tload(Vg, t, va, vb);
    tload(Pg + ((size_t)s0 << 13), t, pa, pb);
    tload(Pg + ((size_t)(s0 + 1) << 13), t, pc, pd);
    tstore(sK, t, ka, kb);
    tstore(sV, t, va, vb);
    tstore(sP + ((s0 & 1) << 13), t, pa, pb);
    tstore(sP + (((s0 + 1) & 1) << 13), t, pc, pd);
  }
  __syncthreads();

  float m_run[4], l_run[4];
  f4 oacc[4];
#pragma unroll
  for (int r = 0; r < 4; ++r) { m_run[r] = -1e30f; l_run[r] = 0.f; }
#pragma unroll
  for (int c = 0; c < 4; ++c) oacc[c] = {0.f, 0.f, 0.f, 0.f};

  const size_t mrowbase = ((size_t)(b << 10) + q0 + 16 * w) * 16;

  for (int kt = 0; kt < 16; ++kt) {
    const int k0 = kt * 64;
    const bool more = kt < 15;

    // ---- issue next-tile loads into registers (latency hides under compute)
    uint4 ka, kb, va, vb, pa, pb;
    if (more) {
      tload(Kg + ((size_t)(kt + 1) << 13), t, ka, kb);
      tload(Vg + ((size_t)(kt + 1) << 13), t, va, vb);
      tload(Pg + ((size_t)(s0 + kt + 2) << 13), t, pa, pb);
    }

    // ---- AC: Q_u . K^T from sK ----
    f4 ac[4];
#pragma unroll
    for (int c = 0; c < 4; ++c) {
      int brow = 16 * c + lc;
      ac[c] = {0.f, 0.f, 0.f, 0.f};
      ac[c] = mfma16(au[0], frag_ld(sK, brow, 0, grp), ac[c]);
      ac[c] = mfma16(au[1], frag_ld(sK, brow, 1, grp), ac[c]);
    }

    // ---- BD: Q_v . P^T over wave-local 80-row window ----
    const int pbase = k0 - q0 + 960;
    const int wbase = 48 - 16 * w;
#pragma unroll
    for (int c2 = 0; c2 < 5; ++c2) {
      int prow0 = pbase + wbase + 16 * c2;
      const unsigned char* slot = sP + ((((unsigned)prow0 >> 6) & 1) << 13);
      int rloc = prow0 & 63;
      f4 z = {0.f, 0.f, 0.f, 0.f};
      z = mfma16(av[0], frag_ld(slot, rloc + lc, 0, grp), z);
      z = mfma16(av[1], frag_ld(slot, rloc + lc, 1, grp), z);
      unsigned lo = (unsigned)f2h(z[0]) | ((unsigned)f2h(z[1]) << 16);
      unsigned hi = (unsigned)f2h(z[2]) | ((unsigned)f2h(z[3]) << 16);
      unsigned char* dst = bdw + (size_t)(((16 * c2 + lc) * 18 + grp * 4) * 2);
      *(unsigned*)dst = lo;
      *(unsigned*)(dst + 4) = hi;
    }

    // ---- score + online softmax (log2 domain) ----
#pragma unroll
    for (int r = 0; r < 4; ++r) {
      const int rr = grp * 4 + r;
      const unsigned long long m64 = Mb[mrowbase + (size_t)rr * 16 + kt];
      float sc[4];
#pragma unroll
      for (int c = 0; c < 4; ++c) {
        const int col = 16 * c + lc;
        float bdf = h2f(*(const unsigned short*)(bdw + (size_t)(((col - rr + 15) * 18 + rr) * 2)));
        float vv = (ac[c][r] + bdf) * 0.18033688f;  // 0.125 * log2(e)
        sc[c] = ((m64 >> col) & 1ull) ? -14427.0f : vv;
      }
      float mx = fmaxf(fmaxf(sc[0], sc[1]), fmaxf(sc[2], sc[3]));
#pragma unroll
      for (int d2 = 1; d2 < 16; d2 <<= 1) mx = fmaxf(mx, __shfl_xor(mx, d2, 64));
      float mnew = fmaxf(m_run[r], mx);
      float scl = exp2f(m_run[r] - mnew);
      float ps = 0.f;
      unsigned short ph[4];
#pragma unroll
      for (int c = 0; c < 4; ++c) {
        float p = exp2f(sc[c] - mnew);
        ps += p;
        ph[c] = f2h(p);
      }
#pragma unroll
      for (int d2 = 1; d2 < 16; d2 <<= 1) ps += __shfl_xor(ps, d2, 64);
      l_run[r] = l_run[r] * scl + ps;
      m_run[r] = mnew;
#pragma unroll
      for (int c = 0; c < 4; ++c) oacc[c][r] *= scl;
      const int sw = (rr & 7) << 4;
#pragma unroll
      for (int c = 0; c < 4; ++c) {
        int off = (rr * 128 + (16 * c + lc) * 2) ^ sw;
        *(unsigned short*)(ppw + off) = ph[c];
      }
    }

    // ---- PV from sV (tile kt) + own ppw ----
    {
      h8 pa0 = frag_ld(ppw, lc, 0, grp);
      h8 pa1 = frag_ld(ppw, lc, 1, grp);
#pragma unroll
      for (int c = 0; c < 4; ++c) {
        int brow = 16 * c + lc;
        oacc[c] = mfma16(pa0, frag_ld(sV, brow, 0, grp), oacc[c]);
        oacc[c] = mfma16(pa1, frag_ld(sV, brow, 1, grp), oacc[c]);
      }
    }

    // ---- staged writes between barriers; single-buffered everywhere ----
    if (more) {
      __syncthreads();  // all waves done reading sK/sV/sP for tile kt
      tstore(sK, t, ka, kb);
      tstore(sV, t, va, vb);
      tstore(sP + (((s0 + kt) & 1) << 13), t, pa, pb);  // seg s0+kt+2 -> its parity slot
      __syncthreads();  // writes visible before next tile's reads
    }
  }

  // ---- epilogue: x[b][t][h*64+d] fp16 ----
#pragma unroll
  for (int c = 0; c < 4; ++c) {
#pragma unroll
    for (int r = 0; r < 4; ++r) {
      int rowq = 16 * w + grp * 4 + r;
      float vv = oacc[c][r] / l_run[r];
      size_t idx = ((size_t)b * Tn + q0 + rowq) * Fn + h * DKn + 16 * c + lc;
      xb[idx] = f2h(vv);
    }
  }
}

}  // namespace

extern "C" void kernel_launch(void* const* d_in, const int* in_sizes, int n_in,
                              void* d_out, int out_size, void* d_ws, size_t ws_size,
                              hipStream_t stream) {
  const float* query = (const float*)d_in[0];
  const float* key = (const float*)d_in[1];
  const float* value = (const float*)d_in[2];
  const void* maskp = d_in[3];
  const float* pos = (const float*)d_in[4];
  const float* Wq = (const float*)d_in[5];
  const float* bq = (const float*)d_in[6];
  const float* Wk = (const float*)d_in[7];
  const float* bk = (const float*)d_in[8];
  const float* Wv = (const float*)d_in[9];
  const float* bv = (const float*)d_in[10];
  const float* Wpos = (const float*)d_in[11];
  const float* Wo = (const float*)d_in[12];
  const float* bo = (const float*)d_in[13];
  const float* pu = (const float*)d_in[14];
  const float* pv = (const float*)d_in[15];
  float* out = (float*)d_out;

  unsigned char* ws = (unsigned char*)d_ws;
  int* flag = (int*)ws;
  size_t o = 256;
  unsigned short* Whs = (unsigned short*)(ws + o); o += (size_t)5 * 262144 * 2;
  unsigned long long* Mb = (unsigned long long*)(ws + o); o += (size_t)Bn * Tn * 16 * 8;
  unsigned short* Qu = (unsigned short*)(ws + o); o += (size_t)Bn * Hn * Tn * DKn * 2;
  unsigned short* Qv = (unsigned short*)(ws + o); o += (size_t)Bn * Hn * Tn * DKn * 2;
  unsigned char* Kws = ws + o; o += (size_t)Bn * Hn * 16 * 8192;
  unsigned char* Vws = ws + o; o += (size_t)Bn * Hn * 16 * 8192;
  unsigned char* Pws = ws + o; o += (size_t)Hn * 32 * 8192;
  unsigned short* xb = (unsigned short*)(ws + o);

  detect_kernel<<<dim3(1), dim3(64), 0, stream>>>((const unsigned int*)maskp, flag);
  maskbits_kernel<<<dim3(2048), dim3(256), 0, stream>>>(maskp, flag, Mb);
  wcvt_kernel<<<dim3(128, 5), dim3(256), 0, stream>>>(Wq, Wk, Wv, Wpos, Wo, Whs);
  qkvp_kernel<<<dim3(128, 8, 4), dim3(256), 0, stream>>>(
      query, key, value, pos, Whs, bq, bk, bv, pu, pv,
      Qu, Qv, Kws, Vws, Pws);
  attn_kernel<<<dim3(1024), dim3(256), 0, stream>>>(Qu, Qv, Kws, Vws, Pws, Mb, xb);
  oproj_kernel<<<dim3(128, 8), dim3(256), 0, stream>>>(xb, Whs + 4 * 262144, bo, out);
}